// Round 4
// baseline (1045.649 us; speedup 1.0000x reference)
//
#include <hip/hip_runtime.h>

#define B_ 4
#define N_ 2048
#define M_ 2048
#define D_ 512
#define H_ 8
#define HID_ELEMS (B_*N_*D_)

typedef __attribute__((ext_vector_type(8))) short s16x8;
typedef __attribute__((ext_vector_type(4))) float f32x4;
typedef __attribute__((ext_vector_type(4))) unsigned short u16x4;

__device__ __forceinline__ float bf2f(unsigned short u) {
  unsigned int x = ((unsigned int)u) << 16;
  return __builtin_bit_cast(float, x);
}
__device__ __forceinline__ unsigned short f2bf(float f) {
  unsigned int x = __builtin_bit_cast(unsigned int, f);
  x += 0x7fffu + ((x >> 16) & 1u);
  return (unsigned short)(x >> 16);
}
#if __has_builtin(__builtin_amdgcn_exp2f)
#define EXP2F(x) __builtin_amdgcn_exp2f(x)
#else
#define EXP2F(x) exp2f(x)
#endif

__device__ __forceinline__ f32x4 mfma16(s16x8 a, s16x8 b, f32x4 c) {
  return __builtin_amdgcn_mfma_f32_16x16x32_bf16(a, b, c, 0, 0, 0);
}
// barrier WITHOUT vmcnt drain: global stores keep draining across heads
__device__ __forceinline__ void bar() {
  asm volatile("s_waitcnt lgkmcnt(0)\n\ts_barrier" ::: "memory");
}

// ---------------- projection GEMM: Out = (A [+Pos]) @ W^T + bias, bf16 out ----
// grid (4, 64), 256 threads. transpose_out: write Vt[b][d][m] instead of [n][d].
__global__ __launch_bounds__(256) void proj_kernel(
    const float* __restrict__ A, const float* __restrict__ Pos,
    const float* __restrict__ W, const float* __restrict__ bias,
    unsigned short* __restrict__ Out, int transpose_out)
{
  __shared__ union {
    struct { unsigned short a[128*88]; unsigned short b[128*88]; } s;
    unsigned short ct[128*136];
  } sm;
  const int tid = threadIdx.x;
  const int lane = tid & 63, w = tid >> 6;
  const int lr = lane & 15, lg = lane >> 4;
  const int wr = w >> 1, wc = w & 1;
  const int n0 = blockIdx.x * 128;   // output-col block (rows of W)
  const int m0 = blockIdx.y * 128;   // row block

  f32x4 acc[4][4];
#pragma unroll
  for (int i = 0; i < 4; ++i)
#pragma unroll
    for (int j = 0; j < 4; ++j) acc[i][j] = (f32x4){0.f,0.f,0.f,0.f};

  for (int kb = 0; kb < 8; ++kb) {
    const int k0 = kb * 64;
#pragma unroll
    for (int rr = 0; rr < 4; ++rr) {
      int row = rr*32 + (tid >> 3);
      int cs  = (tid & 7) * 8;
      const float* ap = A + (size_t)(m0 + row)*512 + k0 + cs;
      f32x4 x0 = *(const f32x4*)ap;
      f32x4 x1 = *(const f32x4*)(ap + 4);
      if (Pos) {
        const float* pp = Pos + (size_t)(m0 + row)*512 + k0 + cs;
        x0 += *(const f32x4*)pp;
        x1 += *(const f32x4*)(pp + 4);
      }
      s16x8 pk;
#pragma unroll
      for (int r = 0; r < 4; ++r) { pk[r] = (short)f2bf(x0[r]); pk[r+4] = (short)f2bf(x1[r]); }
      *(s16x8*)&sm.s.a[row*88 + cs] = pk;

      const float* wp = W + (size_t)(n0 + row)*512 + k0 + cs;
      f32x4 y0 = *(const f32x4*)wp;
      f32x4 y1 = *(const f32x4*)(wp + 4);
      s16x8 pw;
#pragma unroll
      for (int r = 0; r < 4; ++r) { pw[r] = (short)f2bf(y0[r]); pw[r+4] = (short)f2bf(y1[r]); }
      *(s16x8*)&sm.s.b[row*88 + cs] = pw;
    }
    __syncthreads();
#pragma unroll
    for (int kk = 0; kk < 2; ++kk) {
      s16x8 af[4], bf4[4];
#pragma unroll
      for (int i = 0; i < 4; ++i)
        af[i] = *(const s16x8*)&sm.s.a[(wr*64 + i*16 + lr)*88 + kk*32 + lg*8];
#pragma unroll
      for (int j = 0; j < 4; ++j)
        bf4[j] = *(const s16x8*)&sm.s.b[(wc*64 + j*16 + lr)*88 + kk*32 + lg*8];
#pragma unroll
      for (int i = 0; i < 4; ++i)
#pragma unroll
        for (int j = 0; j < 4; ++j)
          acc[i][j] = mfma16(af[i], bf4[j], acc[i][j]);
    }
    __syncthreads();
  }

  if (!transpose_out) {
#pragma unroll
    for (int i = 0; i < 4; ++i)
#pragma unroll
      for (int j = 0; j < 4; ++j) {
        int d = n0 + wc*64 + j*16 + lr;
        float bv = bias[d];
#pragma unroll
        for (int r = 0; r < 4; ++r) {
          int n = m0 + wr*64 + i*16 + lg*4 + r;
          Out[(size_t)n*512 + d] = f2bf(acc[i][j][r] + bv);
        }
      }
  } else {
#pragma unroll
    for (int i = 0; i < 4; ++i)
#pragma unroll
      for (int j = 0; j < 4; ++j) {
        int d = n0 + wc*64 + j*16 + lr;
        float bv = bias[d];
        u16x4 pk;
#pragma unroll
        for (int r = 0; r < 4; ++r) pk[r] = f2bf(acc[i][j][r] + bv);
        int cl = wc*64 + j*16 + lr;
        int nl = wr*64 + i*16 + lg*4;
        *(u16x4*)&sm.ct[cl*136 + nl] = pk;
      }
    __syncthreads();
    int c = tid >> 1, hf = tid & 1;
    int bb = m0 >> 11, mb = m0 & 2047;
    unsigned short* vp = Out + (size_t)(bb*512 + n0 + c)*2048 + mb + hf*64;
#pragma unroll
    for (int j = 0; j < 8; ++j)
      *(s16x8*)(vp + j*8) = *(const s16x8*)&sm.ct[c*136 + hf*64 + j*8];
  }
}

// ---------------- fused attention ----------------
// grid 512 = B * (N/16); 512 threads (8 waves). Heads looped inside.
__global__ __launch_bounds__(512) void attn_kernel(
    const unsigned short* __restrict__ Qm, const unsigned short* __restrict__ Km,
    const unsigned short* __restrict__ Vt, const float* __restrict__ fac,
    const int* __restrict__ am, const int* __restrict__ kmask,
    const float* __restrict__ kw, float* __restrict__ out)
{
  extern __shared__ unsigned char smem[];
  unsigned char* e_b  = smem;            // 65536: e[q=16][m=2048] bf16, swz ^((q&7)<<4)
  unsigned char* f_b  = smem + 65536;    // 65536: fac*kw*0.125*log2e, bf16, same layout
  unsigned char* bm_b = smem + 131072;   // 4096:  mask bits [q=16][64 words], swz ^((q&7)<<2)
  float* rs   = (float*)(smem + 135168); // 8 waves * 16 rows
  float* inv  = (float*)(smem + 135680); // 16
  float* pvr  = (float*)(smem + 135744); // 4 * 256 f32 (PV pair reduce)

  const int tid = threadIdx.x;
  const int w = tid >> 6, lane = tid & 63;
  const int lr = lane & 15, lg = lane >> 4;
  const int gb = blockIdx.x;
  const int b  = gb >> 7;
  const int n0 = (gb & 127) << 4;
  const float SCL = 0.125f * 1.44269504088896f;

  // ---- stage factors * key_weights * scale (bf16) ----
  {
    int q = tid >> 5;
    const float* fr = fac + (size_t)(b*N_ + n0 + q)*M_;
    const float* kr = kw + (size_t)b*M_;
#pragma unroll 4
    for (int j = 0; j < 16; ++j) {
      int m = j*128 + (tid & 31)*4;
      f32x4 fv = __builtin_nontemporal_load((const f32x4*)(fr + m));
      f32x4 kv = *(const f32x4*)(kr + m);
      u16x4 pk;
#pragma unroll
      for (int r = 0; r < 4; ++r) pk[r] = f2bf(fv[r]*kv[r]*SCL);
      *(u16x4*)(f_b + (((q*M_ + m)*2) ^ ((q & 7) << 4))) = pk;
    }
  }
  // ---- stage combined mask bitmap via ballot ----
  {
    const int* kr = kmask + (size_t)b*M_;
    for (int q2 = 0; q2 < 2; ++q2) {
      int q = w*2 + q2;
      const int* ar = am + (size_t)(b*N_ + n0 + q)*M_;
      for (int c = 0; c < 32; ++c) {
        int m = c*64 + lane;
        int v = __builtin_nontemporal_load(ar + m) | kr[m];
        unsigned long long bal = __ballot(v != 0);
        if (lane < 2) {
          int wi = c*2 + lane;
          *(unsigned int*)(bm_b + ((q*256 + wi*4) ^ ((q & 7) << 2))) =
              (unsigned int)(bal >> (lane * 32));
        }
      }
    }
  }
  bar();

  for (int h = 0; h < 8; ++h) {
    // Q fragments (B-operand of swapped QK^T): col q = lr
    const unsigned short* qp = Qm + (size_t)(b*N_ + n0 + lr)*D_ + h*64 + lg*8;
    s16x8 qf0 = *(const s16x8*)qp;
    s16x8 qf1 = *(const s16x8*)(qp + 32);
    float rsum = 0.f;

    const unsigned short* kbase = Km + (size_t)b*M_*D_ + h*64 + lg*8;
    int t = w;
    s16x8 kf0 = *(const s16x8*)(kbase + (size_t)(t*16 + lr)*D_);
    s16x8 kf1 = *(const s16x8*)(kbase + (size_t)(t*16 + lr)*D_ + 32);
    for (int tt = 0; tt < 16; ++tt) {
      s16x8 kn0 = kf0, kn1 = kf1;
      if (tt < 15) {
        int tn = t + 8;
        kn0 = *(const s16x8*)(kbase + (size_t)(tn*16 + lr)*D_);
        kn1 = *(const s16x8*)(kbase + (size_t)(tn*16 + lr)*D_ + 32);
      }
      f32x4 c = {0.f,0.f,0.f,0.f};
      c = mfma16(kf0, qf0, c);   // D[row=m][col=q]
      c = mfma16(kf1, qf1, c);
      int mo = t*16 + lg*4;      // 4 consecutive m per lane, q = lr
      u16x4 fv = *(const u16x4*)(f_b + (((lr*M_ + mo)*2) ^ ((lr & 7) << 4)));
      unsigned int mw = *(const unsigned int*)(bm_b + ((lr*256 + (t>>1)*4) ^ ((lr & 7) << 2)));
      int bit0 = (t & 1)*16 + lg*4;
      u16x4 epk;
#pragma unroll
      for (int r = 0; r < 4; ++r) {
        float s = c[r] * bf2f(fv[r]);
        float e = EXP2F(s);
        e = ((mw >> (bit0 + r)) & 1u) ? 0.f : e;
        rsum += e;
        epk[r] = f2bf(e);
      }
      *(u16x4*)(e_b + (((lr*M_ + mo)*2) ^ ((lr & 7) << 4))) = epk;
      kf0 = kn0; kf1 = kn1;
      t += 8;
    }
    // row sums: reduce over the 4 lane-groups (same lr)
    rsum += __shfl_xor(rsum, 16);
    rsum += __shfl_xor(rsum, 32);
    if (lane < 16) rs[w*16 + lane] = rsum;
    bar();
    if (tid < 16) {
      float l = 0.f;
#pragma unroll
      for (int i = 0; i < 8; ++i) l += rs[i*16 + tid];
      inv[tid] = 1.f / l;
    }
    bar();

    // ---- attn output: attn = e * inv, nontemporal f32 ----
    {
      float* ob = out + HID_ELEMS + (size_t)((b*H_ + h)*N_ + n0)*M_;
      for (int q2 = 0; q2 < 2; ++q2) {
        int q = w*2 + q2;
        float iv = inv[q];
        float* orow = ob + (size_t)q*M_;
#pragma unroll
        for (int it = 0; it < 4; ++it) {
          int m = it*512 + lane*8;
          s16x8 ev = *(const s16x8*)(e_b + (((q*M_ + m)*2) ^ ((q & 7) << 4)));
          f32x4 o0, o1;
#pragma unroll
          for (int r = 0; r < 4; ++r) {
            o0[r] = bf2f((unsigned short)ev[r])   * iv;
            o1[r] = bf2f((unsigned short)ev[r+4]) * iv;
          }
          __builtin_nontemporal_store(o0, (f32x4*)(orow + m));
          __builtin_nontemporal_store(o1, (f32x4*)(orow + m + 4));
        }
      }
    }
    // ---- PV: hidden[q][c] = (sum_m e * V) * inv ----
    {
      int ct = w & 3, kh = w >> 2;
      f32x4 pv = {0.f,0.f,0.f,0.f};
      const unsigned short* vb = Vt + (size_t)(b*D_ + h*64 + ct*16 + lr)*M_ + kh*1024 + lg*8;
#pragma unroll 4
      for (int mk = 0; mk < 32; ++mk) {
        int m = kh*1024 + mk*32 + lg*8;
        s16x8 pa = *(const s16x8*)(e_b + (((lr*M_ + m)*2) ^ ((lr & 7) << 4)));
        s16x8 vf = *(const s16x8*)(vb + mk*32);
        pv = mfma16(pa, vf, pv);
      }
      if (w >= 4) *(f32x4*)(pvr + (w-4)*256 + lane*4) = pv;
      bar();
      if (w < 4) {
        f32x4 o = *(const f32x4*)(pvr + w*256 + lane*4);
#pragma unroll
        for (int r = 0; r < 4; ++r) {
          int q = lg*4 + r;
          out[(size_t)(b*N_ + n0 + q)*D_ + h*64 + ct*16 + lr] = (pv[r] + o[r]) * inv[q];
        }
      }
    }
    bar();  // e_b / pvr reuse next head
  }
}

extern "C" void kernel_launch(void* const* d_in, const int* in_sizes, int n_in,
                              void* d_out, int out_size, void* d_ws, size_t ws_size,
                              hipStream_t stream) {
  (void)in_sizes; (void)n_in; (void)out_size; (void)ws_size;
  const float* input_q = (const float*)d_in[0];
  const float* input_k = (const float*)d_in[1];
  const float* input_v = (const float*)d_in[2];
  const float* pos_q   = (const float*)d_in[3];
  const float* pos_k   = (const float*)d_in[4];
  const float* key_w   = (const float*)d_in[5];
  const int*   key_m   = (const int*)d_in[6];
  const float* att_f   = (const float*)d_in[7];
  const int*   att_m   = (const int*)d_in[8];
  const float* Wq = (const float*)d_in[9];
  const float* bq = (const float*)d_in[10];
  const float* Wk = (const float*)d_in[11];
  const float* bk = (const float*)d_in[12];
  const float* Wv = (const float*)d_in[13];
  const float* bv = (const float*)d_in[14];
  float* out = (float*)d_out;

  unsigned short* q_ws  = (unsigned short*)d_ws;
  unsigned short* k_ws  = q_ws + (size_t)B_*N_*D_;
  unsigned short* vt_ws = k_ws + (size_t)B_*M_*D_;

  dim3 gg(4, 64), bg(256);
  proj_kernel<<<gg, bg, 0, stream>>>(input_q, pos_q, Wq, bq, q_ws, 0);
  proj_kernel<<<gg, bg, 0, stream>>>(input_k, pos_k, Wk, bk, k_ws, 0);
  proj_kernel<<<gg, bg, 0, stream>>>(input_v, nullptr, Wv, bv, vt_ws, 1);

  hipFuncSetAttribute(reinterpret_cast<const void*>(attn_kernel),
                      hipFuncAttributeMaxDynamicSharedMemorySize, 139840);
  attn_kernel<<<dim3(512), dim3(512), 139840, stream>>>(
      q_ws, k_ws, vt_ws, att_f, att_m, key_m, key_w, out);
}